// Round 12
// baseline (196.271 us; speedup 1.0000x reference)
//
#include <hip/hip_runtime.h>
#include <hip/hip_bf16.h>

#define NGRAPH 4096

typedef __attribute__((ext_vector_type(8))) short s16x8;
typedef __attribute__((ext_vector_type(4))) float f32x4;
typedef unsigned int u32;

__device__ inline short f2bf(float f) {
  unsigned u = __float_as_uint(f);
  unsigned r = u + 0x7fffu + ((u >> 16) & 1u);
  return (short)(r >> 16);
}

// Prepack W1 (256x128 fp32, row-major) into bf16 MFMA B-fragment order.
// Fragment f = kt*8 + ct (kt,ct in 0..7). Lane l supplies B[k][c] for
// k = kt*32 + (l>>4)*8 + e (e=0..7), c = ct*16 + (l&15).
__global__ void prepack_w1(const float* __restrict__ W1, s16x8* __restrict__ w1p) {
  int t = blockIdx.x * 256 + threadIdx.x;   // 4096 threads total
  int f = t >> 6, l = t & 63;
  int kt = f >> 3, ct = f & 7;
  int k0 = kt * 32 + ((l >> 4) * 8);
  int c  = ct * 16 + (l & 15);
  s16x8 v;
  #pragma unroll
  for (int e = 0; e < 8; ++e) v[e] = f2bf(W1[(k0 + e) * 128 + c]);
  w1p[f * 64 + l] = v;
}

__device__ inline long long getb(const void* b, int i, int is64) {
  if (is64) return ((const long long*)b)[i];
  return (long long)((const int*)b)[i];
}

__device__ inline int lowb(const void* b, int n, long long v, int is64) {
  int lo = 0, hi = n;
  while (lo < hi) {
    int mid = (lo + hi) >> 1;
    if (getb(b, mid, is64) < v) lo = mid + 1; else hi = mid;
  }
  return lo;
}

__device__ inline int batch_is64(const void* batch, int N) {
  // int64 vs int32 materialization probe: an odd 32-bit word index has a zero
  // high word under int64 (values < 2^31), a near-max sorted id under int32.
  int probe = ((N & 1) == 0) ? (N - 1) : (N - 2);
  return (((const int*)batch)[probe] == 0) ? 1 : 0;
}

// One-time: offs[g] = lower_bound(batch, g).
__global__ void seg_offsets(const void* __restrict__ batch, int* __restrict__ offs, int N) {
  int g = blockIdx.x * 256 + threadIdx.x;
  const int is64 = batch_is64(batch, N);
  if (g <= NGRAPH) offs[g] = lowb(batch, N, (long long)g, is64);
}

__device__ inline float fast_tanh(float v) {
  v = fminf(fmaxf(v, -15.f), 15.f);
  float e = __expf(2.f * v);
  return __fdividef(e - 1.f, e + 1.f);
}

__device__ inline void dma16(const float* src, char* ldsdst) {
  __builtin_amdgcn_global_load_lds(
      (const __attribute__((address_space(1))) u32*)src,
      (__attribute__((address_space(3))) u32*)ldsdst,
      16, 0, 0);   // 16 B/lane: lane l -> ldsdst + l*16
}

// Fused kernel, 32-row tiles, 3 blocks/CU, SELF-SYNCED DMA (no block barrier
// between staging and compute): each wave of wave-pair wp DMAs ALL 16 rows the
// pair consumes (duplicate writes of identical data to the same LDS addrs --
// benign; duplicates are L2 re-reads, HBM fetches once). Each wave then drains
// ONLY ITS OWN DMAs (per-wave s_waitcnt vmcnt(0)) and proceeds straight into
// phase A. Waves/blocks de-phase naturally -> HBM port stays busy during
// compute windows. The pre-exp __syncthreads gives block-wide visibility for
// phases that read other pairs' rows (every wave drained its own DMAs first).
//  Phase A: MFMA gate scores from LDS; B-fragments inline from L2-resident w1p.
//  Phase B: pooling from LDS.
// Scores bounded (|s| <= ||W2||_1 + |b2| ~ 9) -> exp without max-subtraction.
// Cross-block segment joins via atomicAdd (buffers zeroed every call).
__global__ __launch_bounds__(256, 3)
void gate_pool(const float* __restrict__ x, const int* __restrict__ offs,
               const float* __restrict__ b1, const float* __restrict__ W2,
               const float* __restrict__ b2p, const s16x8* __restrict__ w1p,
               float* __restrict__ pooled, float* __restrict__ expout,
               float* __restrict__ segsum, int N)
{
  __shared__ __align__(16) char tile[32 * 1024];  // [row][swizzled 16B chunks]
  __shared__ float sp[2][32];   // [colhalf][node_local] partial scores
  __shared__ float sw[32];      // exp(score) per local row

  const int tid = threadIdx.x;
  const int w = tid >> 6, l = tid & 63;
  const int colhalf = w & 1, wp = w >> 1;
  const int l15 = l & 15, lg = l >> 4;
  const int node0 = blockIdx.x * 32;

  // ---- async DMA: EACH wave stages all 16 rows of its own pair's subtile
  //      (pair wp: rows wp*16 .. wp*16+15; two waves duplicate -> benign) ----
  #pragma unroll
  for (int i = 0; i < 16; ++i) {
    const int r = wp * 16 + i;               // wave-uniform local row
    int grow = node0 + r;
    if (grow >= N) grow = N - 1;             // pad rows: discarded later
    // lane l fills LDS chunk l of row r; source chunk = l ^ (r&7) (swizzle)
    const float* src = x + (size_t)grow * 256 + ((l ^ (r & 7)) << 2);
    dma16(src, tile + r * 1024);
  }

  float b1v[4], w2v[4];
  #pragma unroll
  for (int ct = 0; ct < 4; ++ct) {
    int c = colhalf * 64 + ct * 16 + l15;
    b1v[ct] = b1[c];
    w2v[ct] = W2[c];
  }
  const float b2s = b2p[0];

  // per-wave drain of OWN DMAs (covers the b1/W2 loads too); no block barrier
  asm volatile("s_waitcnt vmcnt(0)" ::: "memory");
  __builtin_amdgcn_sched_barrier(0);

  // ---- Phase A: MFMA gate scores; wave-pair wp owns local rows wp*16..+15,
  //      A-fragments from LDS (rows this wave itself staged), B inline ----
  {
    const int r0 = wp * 16 + l15;
    const char* p0 = tile + r0 * 1024;
    const int s0 = (r0 & 7);

    f32x4 acc0 = {0.f,0.f,0.f,0.f}, acc1 = {0.f,0.f,0.f,0.f};
    f32x4 acc2 = {0.f,0.f,0.f,0.f}, acc3 = {0.f,0.f,0.f,0.f};
    #pragma unroll
    for (int kt = 0; kt < 8; ++kt) {
      const int cc = kt * 8 + lg * 2;        // 16B-chunk index of 8-float slab
      float4 xa = *(const float4*)(p0 + (((cc    ) ^ s0) << 4));
      float4 xb = *(const float4*)(p0 + (((cc + 1) ^ s0) << 4));
      const s16x8* wb = w1p + (kt * 8 + colhalf * 4) * 64 + l;   // L2-resident
      s16x8 bf0 = wb[0], bf1 = wb[64], bf2 = wb[128], bf3 = wb[192];
      s16x8 a;
      a[0] = f2bf(xa.x); a[1] = f2bf(xa.y); a[2] = f2bf(xa.z); a[3] = f2bf(xa.w);
      a[4] = f2bf(xb.x); a[5] = f2bf(xb.y); a[6] = f2bf(xb.z); a[7] = f2bf(xb.w);
      acc0 = __builtin_amdgcn_mfma_f32_16x16x32_bf16(a, bf0, acc0, 0, 0, 0);
      acc1 = __builtin_amdgcn_mfma_f32_16x16x32_bf16(a, bf1, acc1, 0, 0, 0);
      acc2 = __builtin_amdgcn_mfma_f32_16x16x32_bf16(a, bf2, acc2, 0, 0, 0);
      acc3 = __builtin_amdgcn_mfma_f32_16x16x32_bf16(a, bf3, acc3, 0, 0, 0);
    }
    // h = tanh(acc + b1); partial score = sum h*W2 over this wave's 64 cols.
    // D layout: node-in-tile = 4*lg + r, hidden-col = ct*16 + l15.
    float part[4];
    #pragma unroll
    for (int r = 0; r < 4; ++r) {
      part[r] = colhalf ? 0.f : b2s;
      part[r] += fast_tanh(acc0[r] + b1v[0]) * w2v[0];
      part[r] += fast_tanh(acc1[r] + b1v[1]) * w2v[1];
      part[r] += fast_tanh(acc2[r] + b1v[2]) * w2v[2];
      part[r] += fast_tanh(acc3[r] + b1v[3]) * w2v[3];
    }
    #pragma unroll
    for (int m = 1; m <= 8; m <<= 1) {
      #pragma unroll
      for (int r = 0; r < 4; ++r) part[r] += __shfl_xor(part[r], m, 64);
    }
    if (l15 == 0) {
      #pragma unroll
      for (int r = 0; r < 4; ++r)
        sp[colhalf][wp * 16 + lg * 4 + r] = part[r];
    }
  }
  __syncthreads();   // all waves drained own DMAs before here -> tile + sp visible

  // combine halves, exponentiate (no max needed: |score| <= ~9), store
  if (tid < 32) {
    int node = node0 + tid;
    float e = 0.f;
    if (node < N) {
      e = __expf(sp[0][tid] + sp[1][tid]);
      expout[node] = e;                 // unnormalized weight, fixed in finalize
    }
    sw[tid] = e;
  }
  __syncthreads();

  // ---- Phase B: pooling from LDS, col = tid ----
  const int nmax = min(32, N - node0);
  // g: graph containing node0 (upper_bound on offs)
  int g;
  {
    int lo = 0, hi = NGRAPH - 1;
    while (lo < hi) {
      int mid = (lo + hi) >> 1;
      if (offs[mid + 1] <= node0) lo = mid + 1; else hi = mid;
    }
    g = lo;
  }
  const int ccb = tid >> 2, cib = (tid & 3) << 2;   // chunk + in-chunk byte
  int r = 0;
  int nb = offs[g + 1];
  while (r < nmax) {
    const int rend = min(nb - node0, nmax);
    float pacc = 0.f, wsum = 0.f;
    for (; r + 8 <= rend; r += 8) {
      float xv[8], wv[8];
      #pragma unroll
      for (int u = 0; u < 8; ++u) {
        const int rr = r + u;
        xv[u] = *(const float*)(tile + rr * 1024 + (((ccb ^ (rr & 7)) << 4) | cib));
        wv[u] = sw[rr];
      }
      #pragma unroll
      for (int u = 0; u < 8; ++u) {
        pacc += wv[u] * xv[u];
        wsum += wv[u];
      }
    }
    for (; r < rend; ++r) {
      float wv = sw[r];
      pacc += wv * *(const float*)(tile + r * 1024 + (((ccb ^ (r & 7)) << 4) | cib));
      wsum += wv;
    }
    if (wsum > 0.f) {
      atomicAdd(&pooled[(size_t)g * 256 + tid], pacc);
      if (tid == 0) atomicAdd(&segsum[g], wsum);
    }
    if (rend >= nmax) break;
    ++g;
    nb = offs[g + 1];
  }
}

// Finalize: pooled /= segsum (0 for empty graphs), weights = exp/segsum[batch].
__global__ void finalize(float* __restrict__ pooled, float* __restrict__ wts,
                         const float* __restrict__ segsum,
                         const void* __restrict__ batch, int N)
{
  int f = blockIdx.x * 256 + threadIdx.x;
  if (f < NGRAPH * 256) {
    int g = f >> 8;
    float s = segsum[g];
    pooled[f] = (s > 0.f) ? pooled[f] / s : 0.f;
  } else {
    int n = f - NGRAPH * 256;
    if (n < N) {
      const int is64 = batch_is64(batch, N);
      int g = (int)getb(batch, n, is64);
      wts[n] = wts[n] / segsum[g];
    }
  }
}

extern "C" void kernel_launch(void* const* d_in, const int* in_sizes, int n_in,
                              void* d_out, int out_size, void* d_ws, size_t ws_size,
                              hipStream_t stream) {
  const float* x     = (const float*)d_in[0];
  const void*  batch = d_in[1];
  const float* W1    = (const float*)d_in[2];
  const float* b1    = (const float*)d_in[3];
  const float* W2    = (const float*)d_in[4];
  const float* b2    = (const float*)d_in[5];
  const int N = in_sizes[0] / 256;

  float* pooled = (float*)d_out;                          // 4096*256
  float* wout   = (float*)d_out + (size_t)NGRAPH * 256;   // N: exp(s), then weights
  s16x8* w1p    = (s16x8*)d_ws;                           // 64 KB
  int*   offs   = (int*)((char*)d_ws + 64 * 1024);        // 4097 * 4 B
  float* segsum = (float*)((char*)d_ws + 96 * 1024);      // 4096 * 4 B

  // Atomic accumulators must start at zero EVERY call (graph replays included).
  hipMemsetAsync(pooled, 0, (size_t)NGRAPH * 256 * sizeof(float), stream);
  hipMemsetAsync(segsum, 0, (size_t)NGRAPH * sizeof(float), stream);

  prepack_w1<<<16, 256, 0, stream>>>(W1, w1p);
  seg_offsets<<<17, 256, 0, stream>>>(batch, offs, N);
  gate_pool<<<(N + 31) / 32, 256, 0, stream>>>(x, offs, b1, W2, b2, w1p,
                                               pooled, wout, segsum, N);
  const int tot = NGRAPH * 256 + N;
  finalize<<<(tot + 255) / 256, 256, 0, stream>>>(pooled, wout, segsum, batch, N);
}

// Round 13
// 191.822 us; speedup vs baseline: 1.0232x; 1.0232x over previous
//
#include <hip/hip_runtime.h>
#include <hip/hip_bf16.h>

#define NGRAPH 4096

typedef __attribute__((ext_vector_type(8))) short s16x8;
typedef __attribute__((ext_vector_type(4))) float f32x4;
typedef unsigned int u32;

__device__ inline short f2bf(float f) {
  unsigned u = __float_as_uint(f);
  unsigned r = u + 0x7fffu + ((u >> 16) & 1u);
  return (short)(r >> 16);
}

// Prepack W1 (256x128 fp32, row-major) into bf16 MFMA B-fragment order.
// Fragment f = kt*8 + ct (kt,ct in 0..7). Lane l supplies B[k][c] for
// k = kt*32 + (l>>4)*8 + e (e=0..7), c = ct*16 + (l&15).
__global__ void prepack_w1(const float* __restrict__ W1, s16x8* __restrict__ w1p) {
  int t = blockIdx.x * 256 + threadIdx.x;   // 4096 threads total
  int f = t >> 6, l = t & 63;
  int kt = f >> 3, ct = f & 7;
  int k0 = kt * 32 + ((l >> 4) * 8);
  int c  = ct * 16 + (l & 15);
  s16x8 v;
  #pragma unroll
  for (int e = 0; e < 8; ++e) v[e] = f2bf(W1[(k0 + e) * 128 + c]);
  w1p[f * 64 + l] = v;
}

__device__ inline long long getb(const void* b, int i, int is64) {
  if (is64) return ((const long long*)b)[i];
  return (long long)((const int*)b)[i];
}

__device__ inline int lowb(const void* b, int n, long long v, int is64) {
  int lo = 0, hi = n;
  while (lo < hi) {
    int mid = (lo + hi) >> 1;
    if (getb(b, mid, is64) < v) lo = mid + 1; else hi = mid;
  }
  return lo;
}

__device__ inline int batch_is64(const void* batch, int N) {
  // int64 vs int32 materialization probe: an odd 32-bit word index has a zero
  // high word under int64 (values < 2^31), a near-max sorted id under int32.
  int probe = ((N & 1) == 0) ? (N - 1) : (N - 2);
  return (((const int*)batch)[probe] == 0) ? 1 : 0;
}

// One-time: offs[g] = lower_bound(batch, g).
__global__ void seg_offsets(const void* __restrict__ batch, int* __restrict__ offs, int N) {
  int g = blockIdx.x * 256 + threadIdx.x;
  const int is64 = batch_is64(batch, N);
  if (g <= NGRAPH) offs[g] = lowb(batch, N, (long long)g, is64);
}

__device__ inline float fast_tanh(float v) {
  v = fminf(fmaxf(v, -15.f), 15.f);
  float e = __expf(2.f * v);
  return __fdividef(e - 1.f, e + 1.f);
}

__device__ inline void dma16(const float* src, char* ldsdst) {
  __builtin_amdgcn_global_load_lds(
      (const __attribute__((address_space(1))) u32*)src,
      (__attribute__((address_space(3))) u32*)ldsdst,
      16, 0, 0);   // 16 B/lane: lane l -> ldsdst + l*16
}

// Fused kernel, MINI-BLOCKS for stream de-phasing: 128 threads (1 wave-pair),
// 16-row tile, ~17 KB LDS -> ~9 resident blocks/CU. Many small independent
// streams at random phases keep the HBM/DMA port busy while any one block
// computes -- replaces R8-R12's attempts at manual overlap inside big blocks.
//  DMA: the pair's 2 waves stage 8 rows each (async global_load_lds, source
//       chunk pre-swizzled l^(r&7)); __syncthreads drains.
//  Phase A: MFMA gate scores from LDS; wave w = colhalf (64 of 128 hidden
//           cols); B-fragments inline from L2-resident w1p.
//  Phase B: pooling from LDS; each thread owns cols tid and tid+128.
// Scores bounded (|s| <= ||W2||_1 + |b2| ~ 9) -> exp without max-subtraction.
// Cross-block segment joins via atomicAdd (buffers zeroed every call).
__global__ __launch_bounds__(128, 3)
void gate_pool(const float* __restrict__ x, const int* __restrict__ offs,
               const float* __restrict__ b1, const float* __restrict__ W2,
               const float* __restrict__ b2p, const s16x8* __restrict__ w1p,
               float* __restrict__ pooled, float* __restrict__ expout,
               float* __restrict__ segsum, int N)
{
  __shared__ __align__(16) char tile[16 * 1024];  // [row][swizzled 16B chunks]
  __shared__ float sp[2][16];   // [colhalf][node_local] partial scores
  __shared__ float sw[16];      // exp(score) per local row

  const int tid = threadIdx.x;
  const int w = tid >> 6, l = tid & 63;
  const int colhalf = w;                    // wave 0 -> cols 0..63, wave 1 -> 64..127
  const int l15 = l & 15, lg = l >> 4;
  const int node0 = blockIdx.x * 16;

  // ---- async DMA: wave w stages rows w, w+2, ..., w+14 (1 KB each) ----
  #pragma unroll
  for (int i = 0; i < 8; ++i) {
    const int r = i * 2 + w;                 // local row (wave-uniform)
    int grow = node0 + r;
    if (grow >= N) grow = N - 1;             // pad rows: discarded later
    // lane l fills LDS chunk l of row r; source chunk = l ^ (r&7) (swizzle)
    const float* src = x + (size_t)grow * 256 + ((l ^ (r & 7)) << 2);
    dma16(src, tile + r * 1024);
  }

  float b1v[4], w2v[4];
  #pragma unroll
  for (int ct = 0; ct < 4; ++ct) {
    int c = colhalf * 64 + ct * 16 + l15;
    b1v[ct] = b1[c];
    w2v[ct] = W2[c];
  }
  const float b2s = b2p[0];

  __syncthreads();   // drains vmcnt(0) -> tile ready (2-wave barrier, cheap)

  // ---- Phase A: MFMA gate scores, rows 0..15, A-frags from LDS, B inline ----
  {
    const int r0 = l15;
    const char* p0 = tile + r0 * 1024;
    const int s0 = (r0 & 7);

    f32x4 acc0 = {0.f,0.f,0.f,0.f}, acc1 = {0.f,0.f,0.f,0.f};
    f32x4 acc2 = {0.f,0.f,0.f,0.f}, acc3 = {0.f,0.f,0.f,0.f};
    #pragma unroll
    for (int kt = 0; kt < 8; ++kt) {
      const int cc = kt * 8 + lg * 2;        // 16B-chunk index of 8-float slab
      float4 xa = *(const float4*)(p0 + (((cc    ) ^ s0) << 4));
      float4 xb = *(const float4*)(p0 + (((cc + 1) ^ s0) << 4));
      const s16x8* wb = w1p + (kt * 8 + colhalf * 4) * 64 + l;   // L2-resident
      s16x8 bf0 = wb[0], bf1 = wb[64], bf2 = wb[128], bf3 = wb[192];
      s16x8 a;
      a[0] = f2bf(xa.x); a[1] = f2bf(xa.y); a[2] = f2bf(xa.z); a[3] = f2bf(xa.w);
      a[4] = f2bf(xb.x); a[5] = f2bf(xb.y); a[6] = f2bf(xb.z); a[7] = f2bf(xb.w);
      acc0 = __builtin_amdgcn_mfma_f32_16x16x32_bf16(a, bf0, acc0, 0, 0, 0);
      acc1 = __builtin_amdgcn_mfma_f32_16x16x32_bf16(a, bf1, acc1, 0, 0, 0);
      acc2 = __builtin_amdgcn_mfma_f32_16x16x32_bf16(a, bf2, acc2, 0, 0, 0);
      acc3 = __builtin_amdgcn_mfma_f32_16x16x32_bf16(a, bf3, acc3, 0, 0, 0);
    }
    // h = tanh(acc + b1); partial score = sum h*W2 over this wave's 64 cols.
    // D layout: node-in-tile = 4*lg + r, hidden-col = ct*16 + l15.
    float part[4];
    #pragma unroll
    for (int r = 0; r < 4; ++r) {
      part[r] = colhalf ? 0.f : b2s;
      part[r] += fast_tanh(acc0[r] + b1v[0]) * w2v[0];
      part[r] += fast_tanh(acc1[r] + b1v[1]) * w2v[1];
      part[r] += fast_tanh(acc2[r] + b1v[2]) * w2v[2];
      part[r] += fast_tanh(acc3[r] + b1v[3]) * w2v[3];
    }
    #pragma unroll
    for (int m = 1; m <= 8; m <<= 1) {
      #pragma unroll
      for (int r = 0; r < 4; ++r) part[r] += __shfl_xor(part[r], m, 64);
    }
    if (l15 == 0) {
      #pragma unroll
      for (int r = 0; r < 4; ++r)
        sp[colhalf][lg * 4 + r] = part[r];
    }
  }
  __syncthreads();

  // combine halves, exponentiate (no max needed: |score| <= ~9), store
  if (tid < 16) {
    int node = node0 + tid;
    float e = 0.f;
    if (node < N) {
      e = __expf(sp[0][tid] + sp[1][tid]);
      expout[node] = e;                 // unnormalized weight, fixed in finalize
    }
    sw[tid] = e;
  }
  __syncthreads();

  // ---- Phase B: pooling from LDS; thread owns cols tid and tid+128 ----
  const int nmax = min(16, N - node0);
  // g: graph containing node0 (upper_bound on offs)
  int g;
  {
    int lo = 0, hi = NGRAPH - 1;
    while (lo < hi) {
      int mid = (lo + hi) >> 1;
      if (offs[mid + 1] <= node0) lo = mid + 1; else hi = mid;
    }
    g = lo;
  }
  const int c0 = tid, c1 = tid + 128;
  const int ccb0 = c0 >> 2, cib0 = (c0 & 3) << 2;
  const int ccb1 = c1 >> 2, cib1 = (c1 & 3) << 2;
  int r = 0;
  int nb = offs[g + 1];
  while (r < nmax) {
    const int rend = min(nb - node0, nmax);
    float pacc0 = 0.f, pacc1 = 0.f, wsum = 0.f;
    for (; r + 4 <= rend; r += 4) {
      float xv0[4], xv1[4], wv[4];
      #pragma unroll
      for (int u = 0; u < 4; ++u) {
        const int rr = r + u;
        const char* rp = tile + rr * 1024;
        xv0[u] = *(const float*)(rp + (((ccb0 ^ (rr & 7)) << 4) | cib0));
        xv1[u] = *(const float*)(rp + (((ccb1 ^ (rr & 7)) << 4) | cib1));
        wv[u] = sw[rr];
      }
      #pragma unroll
      for (int u = 0; u < 4; ++u) {
        pacc0 += wv[u] * xv0[u];
        pacc1 += wv[u] * xv1[u];
        wsum  += wv[u];
      }
    }
    for (; r < rend; ++r) {
      float wv = sw[r];
      const char* rp = tile + r * 1024;
      pacc0 += wv * *(const float*)(rp + (((ccb0 ^ (r & 7)) << 4) | cib0));
      pacc1 += wv * *(const float*)(rp + (((ccb1 ^ (r & 7)) << 4) | cib1));
      wsum  += wv;
    }
    if (wsum > 0.f) {
      atomicAdd(&pooled[(size_t)g * 256 + c0], pacc0);
      atomicAdd(&pooled[(size_t)g * 256 + c1], pacc1);
      if (tid == 0) atomicAdd(&segsum[g], wsum);
    }
    if (rend >= nmax) break;
    ++g;
    nb = offs[g + 1];
  }
}

// Finalize: pooled /= segsum (0 for empty graphs), weights = exp/segsum[batch].
__global__ void finalize(float* __restrict__ pooled, float* __restrict__ wts,
                         const float* __restrict__ segsum,
                         const void* __restrict__ batch, int N)
{
  int f = blockIdx.x * 256 + threadIdx.x;
  if (f < NGRAPH * 256) {
    int g = f >> 8;
    float s = segsum[g];
    pooled[f] = (s > 0.f) ? pooled[f] / s : 0.f;
  } else {
    int n = f - NGRAPH * 256;
    if (n < N) {
      const int is64 = batch_is64(batch, N);
      int g = (int)getb(batch, n, is64);
      wts[n] = wts[n] / segsum[g];
    }
  }
}

extern "C" void kernel_launch(void* const* d_in, const int* in_sizes, int n_in,
                              void* d_out, int out_size, void* d_ws, size_t ws_size,
                              hipStream_t stream) {
  const float* x     = (const float*)d_in[0];
  const void*  batch = d_in[1];
  const float* W1    = (const float*)d_in[2];
  const float* b1    = (const float*)d_in[3];
  const float* W2    = (const float*)d_in[4];
  const float* b2    = (const float*)d_in[5];
  const int N = in_sizes[0] / 256;

  float* pooled = (float*)d_out;                          // 4096*256
  float* wout   = (float*)d_out + (size_t)NGRAPH * 256;   // N: exp(s), then weights
  s16x8* w1p    = (s16x8*)d_ws;                           // 64 KB
  int*   offs   = (int*)((char*)d_ws + 64 * 1024);        // 4097 * 4 B
  float* segsum = (float*)((char*)d_ws + 96 * 1024);      // 4096 * 4 B

  // Atomic accumulators must start at zero EVERY call (graph replays included).
  hipMemsetAsync(pooled, 0, (size_t)NGRAPH * 256 * sizeof(float), stream);
  hipMemsetAsync(segsum, 0, (size_t)NGRAPH * sizeof(float), stream);

  prepack_w1<<<16, 256, 0, stream>>>(W1, w1p);
  seg_offsets<<<17, 256, 0, stream>>>(batch, offs, N);
  gate_pool<<<(N + 15) / 16, 128, 0, stream>>>(x, offs, b1, W2, b2, w1p,
                                               pooled, wout, segsum, N);
  const int tot = NGRAPH * 256 + N;
  finalize<<<(tot + 255) / 256, 256, 0, stream>>>(pooled, wout, segsum, batch, N);
}